// Round 8
// baseline (874.797 us; speedup 1.0000x reference)
//
#include <hip/hip_runtime.h>
#include <math.h>

#define EPS_OT 0.05f
#define INV_EPS 20.0f

typedef unsigned short ushort_t;
typedef __attribute__((ext_vector_type(8))) short short8;
typedef __attribute__((ext_vector_type(4))) float f32x4;
union Pk { uint4 u; short8 s; };

__device__ __forceinline__ unsigned int f2bf(float f) {  // RNE f32->bf16
  unsigned int u = __float_as_uint(f);
  return (u + 0x7FFFu + ((u >> 16) & 1u)) >> 16;
}
__device__ __forceinline__ float bf2f(unsigned int u) { return __uint_as_float(u << 16); }

// ---------------- pack: fp32 -> hi/lo bf16 (one-time) ----------------
__global__ __launch_bounds__(256) void pack_k(const float* __restrict__ F_t,
                                              const float* __restrict__ F_s,
                                              const float* __restrict__ Wq,
                                              const float* __restrict__ Wk,
                                              const float* __restrict__ Wv,
                                              const float* __restrict__ Wp,
                                              ushort_t* __restrict__ Fth, ushort_t* __restrict__ Ftl,
                                              ushort_t* __restrict__ Fsh, ushort_t* __restrict__ Fsl,
                                              ushort_t* __restrict__ Wqh, ushort_t* __restrict__ Wql,
                                              ushort_t* __restrict__ Wkh, ushort_t* __restrict__ Wkl,
                                              ushort_t* __restrict__ Wvh, ushort_t* __restrict__ Wvl,
                                              ushort_t* __restrict__ Wph) {
  const int blk = blockIdx.x;
  const float* src; ushort_t* dh; ushort_t* dl; size_t off;
  if (blk < 2048)      { src = F_t; dh = Fth; dl = Ftl; off = (size_t)blk * 1024; }
  else if (blk < 6656) { src = F_s; dh = Fsh; dl = Fsl; off = (size_t)(blk - 2048) * 1024; }
  else if (blk < 6912) { src = Wq;  dh = Wqh; dl = Wql; off = (size_t)(blk - 6656) * 1024; }
  else if (blk < 7168) { src = Wk;  dh = Wkh; dl = Wkl; off = (size_t)(blk - 6912) * 1024; }
  else if (blk < 7424) { src = Wv;  dh = Wvh; dl = Wvl; off = (size_t)(blk - 7168) * 1024; }
  else                 { src = Wp;  dh = Wph; dl = nullptr; off = (size_t)(blk - 7424) * 1024; }
  const size_t i = off + (size_t)threadIdx.x * 4;
  float4 f = *(const float4*)(src + i);
  unsigned int h0 = f2bf(f.x), h1 = f2bf(f.y), h2 = f2bf(f.z), h3 = f2bf(f.w);
  uint2 hh; hh.x = h0 | (h1 << 16); hh.y = h2 | (h3 << 16);
  *(uint2*)(dh + i) = hh;
  if (dl) {
    uint2 ll;
    ll.x = f2bf(f.x - bf2f(h0)) | (f2bf(f.y - bf2f(h1)) << 16);
    ll.y = f2bf(f.z - bf2f(h2)) | (f2bf(f.w - bf2f(h3)) << 16);
    *(uint2*)(dl + i) = ll;
  }
}

// ====== hi/lo GEMM main loop on pre-packed bf16 (64x64 tile, K=512, 3-MFMA) ======
#define GEMM_HL_BODY()                                                                      \
  f32x4 acc[4] = {};                                                                        \
  for (int k0 = 0; k0 < 512; k0 += 64) {                                                    \
    uint4 a0 = *(const uint4*)(Xp_h + k0), a1 = *(const uint4*)(Xp_h + k0 + 8);             \
    uint4 b0 = *(const uint4*)(Xp_l + k0), b1 = *(const uint4*)(Xp_l + k0 + 8);             \
    uint4 c0 = *(const uint4*)(Wp_h + k0), c1 = *(const uint4*)(Wp_h + k0 + 8);             \
    uint4 d0 = *(const uint4*)(Wp_l + k0), d1 = *(const uint4*)(Wp_l + k0 + 8);             \
    __syncthreads();                                                                        \
    *(uint4*)&Xh[r][cg * 16] = a0; *(uint4*)&Xh[r][cg * 16 + 8] = a1;                       \
    *(uint4*)&Xl[r][cg * 16] = b0; *(uint4*)&Xl[r][cg * 16 + 8] = b1;                       \
    *(uint4*)&Wh[r][cg * 16] = c0; *(uint4*)&Wh[r][cg * 16 + 8] = c1;                       \
    *(uint4*)&Wl[r][cg * 16] = d0; *(uint4*)&Wl[r][cg * 16 + 8] = d1;                       \
    __syncthreads();                                                                        \
    _Pragma("unroll") for (int kst = 0; kst < 2; ++kst) {                                   \
      short8 ah = *(const short8*)&Xh[16 * w + li][kst * 32 + 8 * lg];                      \
      short8 al = *(const short8*)&Xl[16 * w + li][kst * 32 + 8 * lg];                      \
      _Pragma("unroll") for (int nt = 0; nt < 4; ++nt) {                                    \
        short8 bh = *(const short8*)&Wh[nt * 16 + li][kst * 32 + 8 * lg];                   \
        short8 bl = *(const short8*)&Wl[nt * 16 + li][kst * 32 + 8 * lg];                   \
        acc[nt] = __builtin_amdgcn_mfma_f32_16x16x32_bf16(ah, bh, acc[nt], 0, 0, 0);        \
        acc[nt] = __builtin_amdgcn_mfma_f32_16x16x32_bf16(ah, bl, acc[nt], 0, 0, 0);        \
        acc[nt] = __builtin_amdgcn_mfma_f32_16x16x32_bf16(al, bh, acc[nt], 0, 0, 0);        \
      }                                                                                     \
    }                                                                                       \
  }

// ====== plain bf16 GEMM main loop (64x64 tile, K=512, 1-MFMA) ======
#define GEMM_PL_BODY()                                                                      \
  f32x4 acc[4] = {};                                                                        \
  for (int k0 = 0; k0 < 512; k0 += 64) {                                                    \
    uint4 a0 = *(const uint4*)(Xp_h + k0), a1 = *(const uint4*)(Xp_h + k0 + 8);             \
    uint4 c0 = *(const uint4*)(Wp_h + k0), c1 = *(const uint4*)(Wp_h + k0 + 8);             \
    __syncthreads();                                                                        \
    *(uint4*)&Xh[r][cg * 16] = a0; *(uint4*)&Xh[r][cg * 16 + 8] = a1;                       \
    *(uint4*)&Wh[r][cg * 16] = c0; *(uint4*)&Wh[r][cg * 16 + 8] = c1;                       \
    __syncthreads();                                                                        \
    _Pragma("unroll") for (int kst = 0; kst < 2; ++kst) {                                   \
      short8 ah = *(const short8*)&Xh[16 * w + li][kst * 32 + 8 * lg];                      \
      _Pragma("unroll") for (int nt = 0; nt < 4; ++nt) {                                    \
        short8 bh = *(const short8*)&Wh[nt * 16 + li][kst * 32 + 8 * lg];                   \
        acc[nt] = __builtin_amdgcn_mfma_f32_16x16x32_bf16(ah, bh, acc[nt], 0, 0, 0);        \
      }                                                                                     \
    }                                                                                       \
  }

// ------- fused GEMM + per-head l2norm -> hi/lo bf16 [B*H][Nn][64] (q and k) -------
__global__ __launch_bounds__(256) void gemmnorm2_k(const ushort_t* __restrict__ Xg_h,
                                                   const ushort_t* __restrict__ Xg_l,
                                                   const ushort_t* __restrict__ Wg_h,
                                                   const ushort_t* __restrict__ Wg_l,
                                                   const float* __restrict__ bias,
                                                   ushort_t* __restrict__ oh,
                                                   ushort_t* __restrict__ ol, int Nn) {
  __shared__ ushort_t Xh[64][72], Xl[64][72], Wh[64][72], Wl[64][72];
  const int tid = threadIdx.x;
  const int w = tid >> 6, l = tid & 63, li = l & 15, lg = l >> 4;
  const int r = tid >> 2, cg = tid & 3;
  const int m0 = blockIdx.x << 6;
  const int h = blockIdx.y, n0 = h << 6;
  const ushort_t* Xp_h = Xg_h + (size_t)(m0 + r) * 512 + cg * 16;
  const ushort_t* Xp_l = Xg_l + (size_t)(m0 + r) * 512 + cg * 16;
  const ushort_t* Wp_h = Wg_h + (size_t)(n0 + r) * 512 + cg * 16;
  const ushort_t* Wp_l = Wg_l + (size_t)(n0 + r) * 512 + cg * 16;
  GEMM_HL_BODY()
  float v[4][4];
  float ss[4] = {0.f, 0.f, 0.f, 0.f};
#pragma unroll
  for (int nt = 0; nt < 4; ++nt) {
    float bb = bias[n0 + nt * 16 + li];
#pragma unroll
    for (int reg = 0; reg < 4; ++reg) {
      float y = acc[nt][reg] + bb;
      v[nt][reg] = y;
      ss[reg] = fmaf(y, y, ss[reg]);
    }
  }
#pragma unroll
  for (int off = 1; off < 16; off <<= 1)
#pragma unroll
    for (int reg = 0; reg < 4; ++reg) ss[reg] += __shfl_xor(ss[reg], off, 64);
  const int b = m0 / Nn;
  const int nbase = m0 - b * Nn;
  const size_t base = ((size_t)(b * 8 + h) * Nn + nbase + 16 * w + 4 * lg) * 64;
#pragma unroll
  for (int reg = 0; reg < 4; ++reg) {
    float inv = 1.0f / fmaxf(sqrtf(ss[reg]), 1e-12f);
#pragma unroll
    for (int nt = 0; nt < 4; ++nt) {
      float y = v[nt][reg] * inv;
      unsigned int hi = f2bf(y);
      size_t idx = base + (size_t)reg * 64 + nt * 16 + li;
      oh[idx] = (ushort_t)hi;
      ol[idx] = (ushort_t)f2bf(y - bf2f(hi));
    }
  }
}

// ------- fused plain-bf16 GEMM + transpose: vt[s][c 0..63][j 0..575] (v path) -------
__global__ __launch_bounds__(256) void gemmtrans2_k(const ushort_t* __restrict__ Xg_h,
                                                    const ushort_t* __restrict__ Wg_h,
                                                    const float* __restrict__ bias,
                                                    ushort_t* __restrict__ vt) {
  __shared__ ushort_t Xh[64][72], Wh[64][72];
  __shared__ ushort_t Vs[64 * 73];
  const int tid = threadIdx.x;
  const int w = tid >> 6, l = tid & 63, li = l & 15, lg = l >> 4;
  const int r = tid >> 2, cg = tid & 3;
  const int m0 = blockIdx.x << 6;
  const int h = blockIdx.y, n0 = h << 6;
  const ushort_t* Xp_h = Xg_h + (size_t)(m0 + r) * 512 + cg * 16;
  const ushort_t* Wp_h = Wg_h + (size_t)(n0 + r) * 512 + cg * 16;
  GEMM_PL_BODY()
#pragma unroll
  for (int nt = 0; nt < 4; ++nt) {
    float bb = bias[n0 + nt * 16 + li];
#pragma unroll
    for (int reg = 0; reg < 4; ++reg)
      Vs[(16 * w + 4 * lg + reg) * 73 + nt * 16 + li] = (ushort_t)f2bf(acc[nt][reg] + bb);
  }
  __syncthreads();
  const int a9 = m0 >> 6;
  const int b = a9 / 9;
  const int nbase = m0 - b * 576;
  const int s = b * 8 + h;
  const int c = tid >> 2, q4 = tid & 3;
  ushort_t tmp[16];
#pragma unroll
  for (int jj = 0; jj < 16; ++jj) tmp[jj] = Vs[(q4 * 16 + jj) * 73 + c];
  ushort_t* op = vt + ((size_t)s * 64 + c) * 576 + nbase + q4 * 16;
  *(uint4*)op = *(uint4*)&tmp[0];
  *(uint4*)(op + 8) = *(uint4*)&tmp[8];
}

// ------- final plain-bf16 GEMM (scorev-out bf16 @ Wp_h) -> fp32 -------
__global__ __launch_bounds__(256) void gemmplain_k(const ushort_t* __restrict__ Xg_h,
                                                   const ushort_t* __restrict__ Wg_h,
                                                   const float* __restrict__ bias,
                                                   float* __restrict__ Y) {
  __shared__ ushort_t Xh[64][72], Wh[64][72];
  const int tid = threadIdx.x;
  const int w = tid >> 6, l = tid & 63, li = l & 15, lg = l >> 4;
  const int r = tid >> 2, cg = tid & 3;
  const int m0 = blockIdx.x << 6, n0 = blockIdx.y << 6;
  const ushort_t* Xp_h = Xg_h + (size_t)(m0 + r) * 512 + cg * 16;
  const ushort_t* Wp_h = Wg_h + (size_t)(n0 + r) * 512 + cg * 16;
  GEMM_PL_BODY()
#pragma unroll
  for (int nt = 0; nt < 4; ++nt) {
    float bb = bias[n0 + nt * 16 + li];
#pragma unroll
    for (int reg = 0; reg < 4; ++reg)
      Y[(size_t)(m0 + 16 * w + 4 * lg + reg) * 512 + n0 + nt * 16 + li] = acc[nt][reg] + bb;
  }
}

// ============ Sinkhorn v7: fully fused simE + loop + scorev, E never leaves LDS ============
// 2 wgs per (b,h) slice. Phase 0: build 128x576 bf16 E-half in LDS from q,k (hi/lo MFMA,
// k staged 32 rows at a time through an 8KB scratch region). Loop: shift-free Sinkhorn,
// SINGLE-bf16 au/bv (vector rounding << E's own bf16 storage error), 18 MFMA/wave/iter,
// LDS-atomic rsum/colsum, tag-based MALL exchange, 3 barriers/iter. Epilogue: P-transform
// + P@V MFMA straight from LDS-E against vt; output bf16.
#define SK7_SMEM 155648  // 147456 (E) + 8192 (staging/loop scratch overlay)

__global__ __launch_bounds__(1024, 1) void sinkhorn7_k(const ushort_t* __restrict__ qh,
                                                       const ushort_t* __restrict__ ql,
                                                       const ushort_t* __restrict__ kh,
                                                       const ushort_t* __restrict__ kl,
                                                       const ushort_t* __restrict__ vt,
                                                       ushort_t* __restrict__ Y,
                                                       unsigned long long* __restrict__ gpart,
                                                       float C_mu, float C_nu) {
  extern __shared__ char smem[];
  ushort_t* Elds = (ushort_t*)smem;          // [128][576] bf16
  char* scr = smem + 147456;                 // 8192 B overlay region
  ushort_t* khs = (ushort_t*)scr;            // phase0: [32][64] hi
  ushort_t* kls = khs + 2048;                // phase0: [32][64] lo
  float* uu = (float*)scr;                   // loop: 128
  float* vv = uu + 128;                      // 576
  float* rsum = vv + 576;                    // 128
  float* colsum = rsum + 128;                // 576
  ushort_t* au = (ushort_t*)(colsum + 576);  // 128 bf16
  ushort_t* bv = au + 128;                   // 576 bf16  (total 7040 B)

  const int g = blockIdx.x, s = g >> 1, rh = g & 1, pg = g ^ 1;
  const int tid = threadIdx.x, w = tid >> 6, l = tid & 63, li = l & 15, lg = l >> 4;
  unsigned long long* myP = gpart + (size_t)g * 1152;
  const unsigned long long* prP = gpart + (size_t)pg * 1152;

  // ---- wave-owned q A-frags (rows it*16+li of own half), hi/lo ----
  const int it = w & 7, ntp = w >> 3;
  const size_t qoff = ((size_t)(s * 256 + rh * 128 + it * 16 + li)) * 64 + 8 * lg;
  short8 aH0 = *(const short8*)(qh + qoff), aH1 = *(const short8*)(qh + qoff + 32);
  short8 aL0 = *(const short8*)(ql + qoff), aL1 = *(const short8*)(ql + qoff + 32);

  // ---- phase 0: E = bf16(exp((q.k - 1)*20)) built in LDS ----
  for (int jt = 0; jt < 9; ++jt) {
#pragma unroll
    for (int p = 0; p < 2; ++p) {
      const int q = tid & 511;
      const int jr = jt * 64 + p * 32 + (q >> 4);
      const size_t src = ((size_t)(s * 576 + jr)) * 64 + (q & 15) * 4;
      if (tid < 512) ((uint2*)khs)[q] = *(const uint2*)(kh + src);
      else           ((uint2*)kls)[q] = *(const uint2*)(kl + src);
      __syncthreads();
      const ushort_t* kb_h = khs + (ntp * 16 + li) * 64 + 8 * lg;
      const ushort_t* kb_l = kls + (ntp * 16 + li) * 64 + 8 * lg;
      short8 bH0 = *(const short8*)kb_h, bH1 = *(const short8*)(kb_h + 32);
      short8 bL0 = *(const short8*)kb_l, bL1 = *(const short8*)(kb_l + 32);
      f32x4 acc = {0.f, 0.f, 0.f, 0.f};
      acc = __builtin_amdgcn_mfma_f32_16x16x32_bf16(aH0, bH0, acc, 0, 0, 0);
      acc = __builtin_amdgcn_mfma_f32_16x16x32_bf16(aH1, bH1, acc, 0, 0, 0);
      acc = __builtin_amdgcn_mfma_f32_16x16x32_bf16(aH0, bL0, acc, 0, 0, 0);
      acc = __builtin_amdgcn_mfma_f32_16x16x32_bf16(aH1, bL1, acc, 0, 0, 0);
      acc = __builtin_amdgcn_mfma_f32_16x16x32_bf16(aL0, bH0, acc, 0, 0, 0);
      acc = __builtin_amdgcn_mfma_f32_16x16x32_bf16(aL1, bH1, acc, 0, 0, 0);
#pragma unroll
      for (int reg = 0; reg < 4; ++reg) {
        float e = __expf((acc[reg] - 1.0f) * INV_EPS);
        Elds[(it * 16 + 4 * lg + reg) * 576 + jt * 64 + p * 32 + ntp * 16 + li] =
            (ushort_t)f2bf(e);
      }
      __syncthreads();
    }
  }

  // ---- frag extraction (layouts proven in R4/R6) ----
  short8 afr[9];
#pragma unroll
  for (int rt = 0; rt < 8; ++rt)
    afr[rt] = *(const short8*)(Elds + (rt * 16 + li) * 576 + w * 32 + 8 * lg);
  const int rtx = w & 7, ktx = 16 + (w >> 3);
  afr[8] = *(const short8*)(Elds + (rtx * 16 + li) * 576 + ktx * 32 + 8 * lg);
  const int ktB = w >> 2, ntb = (w & 3) * 9;
  short8 bfr[9];
#pragma unroll
  for (int p9 = 0; p9 < 9; ++p9) {
    const ushort_t* p = Elds + (ktB * 32 + 8 * lg) * 576 + (ntb + p9) * 16 + li;
    Pk pk;
    pk.u.x = (unsigned int)p[0]    | ((unsigned int)p[576]  << 16);
    pk.u.y = (unsigned int)p[1152] | ((unsigned int)p[1728] << 16);
    pk.u.z = (unsigned int)p[2304] | ((unsigned int)p[2880] << 16);
    pk.u.w = (unsigned int)p[3456] | ((unsigned int)p[4032] << 16);
    bfr[p9] = pk.s;
  }
  // init loop scratch (overlays phase-0 staging; staging fully consumed)
  if (tid < 128) { uu[tid] = 0.0f; au[tid] = (ushort_t)0x3F80; rsum[tid] = 0.0f; }
  if (tid < 576) { vv[tid] = 0.0f; bv[tid] = (ushort_t)0x3F80; colsum[tid] = 0.0f; }
  __syncthreads();

  for (int t = 0; t < 100; ++t) {
    // ---- A: matvec2 c = E^T.au (atomic colsum); zero rsum for this iter ----
    if (tid < 128) rsum[tid] = 0.0f;
    {
      Pk ah; ah.u = *(const uint4*)(au + ktB * 32 + 8 * lg);
#pragma unroll
      for (int p9 = 0; p9 < 9; ++p9) {
        f32x4 a2 = {0.f, 0.f, 0.f, 0.f};
        a2 = __builtin_amdgcn_mfma_f32_16x16x32_bf16(ah.s, bfr[p9], a2, 0, 0, 0);
        if (l < 16) atomicAdd(&colsum[(ntb + p9) * 16 + l], a2[0]);
      }
    }
    __syncthreads();
    // ---- B: publish colsums (MALL), then matvec1 r = E.bv hides the round trip ----
    const int par = t & 1;
    float csMine = 0.0f;
    if (tid < 576) {
      csMine = colsum[tid];
      unsigned long long pv = (unsigned long long)__float_as_uint(csMine) |
                              ((unsigned long long)(unsigned int)(t + 1) << 32);
      __hip_atomic_store(&myP[par * 576 + tid], pv, __ATOMIC_RELAXED, __HIP_MEMORY_SCOPE_AGENT);
    }
    {
      Pk bh, bhx;
      bh.u = *(const uint4*)(bv + w * 32 + 8 * lg);
      bhx.u = *(const uint4*)(bv + ktx * 32 + 8 * lg);
#pragma unroll
      for (int rt = 0; rt < 8; ++rt) {
        f32x4 a1 = {0.f, 0.f, 0.f, 0.f};
        a1 = __builtin_amdgcn_mfma_f32_16x16x32_bf16(bh.s, afr[rt], a1, 0, 0, 0);
        if (l < 16) atomicAdd(&rsum[rt * 16 + l], a1[0]);
      }
      f32x4 a1 = {0.f, 0.f, 0.f, 0.f};
      a1 = __builtin_amdgcn_mfma_f32_16x16x32_bf16(bhx.s, afr[8], a1, 0, 0, 0);
      if (l < 16) atomicAdd(&rsum[rtx * 16 + l], a1[0]);
    }
    __syncthreads();
    // ---- C: v-update (tid<576, poll partner) | u-update (576..703) | zero colsum ----
    if (tid < 576) {
      const unsigned int tg = (unsigned int)(t + 1);
      unsigned long long p0;
      for (;;) {
        p0 = __hip_atomic_load(&prP[par * 576 + tid], __ATOMIC_RELAXED, __HIP_MEMORY_SCOPE_AGENT);
        if ((unsigned int)(p0 >> 32) == tg) break;
        __builtin_amdgcn_s_sleep(1);
      }
      float vn = C_nu - EPS_OT * __logf(csMine + __uint_as_float((unsigned int)p0));
      vv[tid] = vn;
      bv[tid] = (ushort_t)f2bf(__expf(fminf(fmaxf(vn * INV_EPS, -80.f), 80.f)));
    } else if (tid < 704) {
      const int i = tid - 576;
      float un = C_mu - EPS_OT * __logf(rsum[i]);
      uu[i] = un;
      au[i] = (ushort_t)f2bf(__expf(fminf(fmaxf(un * INV_EPS, -80.f), 80.f)));
    } else {
      for (int j = tid - 704; j < 576; j += 320) colsum[j] = 0.0f;
    }
    __syncthreads();
  }

  // ---- epilogue: P = (1+eps*lnE)*exp(lnE + u_i*20 + v_j*20 + lnN); out = P @ V ----
  if (tid < 576) vv[tid] = vv[tid] * INV_EPS + 11.9012851f;  // + ln(147456)
  __syncthreads();
  {
    const float ga = uu[it * 16 + li] * INV_EPS;
    const int nt0 = ntp * 2, nt1 = nt0 + 1;
    const ushort_t* Erow = Elds + (it * 16 + li) * 576;
    const ushort_t* v0p = vt + ((size_t)s * 64 + nt0 * 16 + li) * 576;
    const ushort_t* v1p = vt + ((size_t)s * 64 + nt1 * 16 + li) * 576;
    f32x4 oa0 = {0.f, 0.f, 0.f, 0.f}, oa1 = {0.f, 0.f, 0.f, 0.f};
    for (int kst = 0; kst < 18; ++kst) {
      const int jb = kst * 32 + 8 * lg;
      Pk eu; eu.u = *(const uint4*)(Erow + jb);
      float pv[8];
#pragma unroll
      for (int jj = 0; jj < 8; ++jj) {
        float e = bf2f((unsigned int)(unsigned short)eu.s[jj]);
        float le = __logf(e);
        pv[jj] = (1.0f + EPS_OT * le) * __expf(le + ga + vv[jb + jj]);
      }
      Pk ph, pl;
#pragma unroll
      for (int jj = 0; jj < 8; ++jj) {
        unsigned int hb = f2bf(pv[jj]);
        ((unsigned short*)&ph.s)[jj] = (unsigned short)hb;
        ((unsigned short*)&pl.s)[jj] = (unsigned short)f2bf(pv[jj] - bf2f(hb));
      }
      Pk v0; v0.u = *(const uint4*)(v0p + jb);
      Pk v1; v1.u = *(const uint4*)(v1p + jb);
      oa0 = __builtin_amdgcn_mfma_f32_16x16x32_bf16(ph.s, v0.s, oa0, 0, 0, 0);
      oa0 = __builtin_amdgcn_mfma_f32_16x16x32_bf16(pl.s, v0.s, oa0, 0, 0, 0);
      oa1 = __builtin_amdgcn_mfma_f32_16x16x32_bf16(ph.s, v1.s, oa1, 0, 0, 0);
      oa1 = __builtin_amdgcn_mfma_f32_16x16x32_bf16(pl.s, v1.s, oa1, 0, 0, 0);
    }
    const int b = s >> 3, h = s & 7;
    const int orow = b * 256 + rh * 128 + it * 16 + 4 * lg;
#pragma unroll
    for (int reg = 0; reg < 4; ++reg) {
      Y[((size_t)(orow + reg) << 9) + h * 64 + nt0 * 16 + li] = (ushort_t)f2bf(oa0[reg]);
      Y[((size_t)(orow + reg) << 9) + h * 64 + nt1 * 16 + li] = (ushort_t)f2bf(oa1[reg]);
    }
  }
}

// ------------------------- final row l2norm (plain division) -------------------------
__global__ __launch_bounds__(256) void rownorm_k(const float* __restrict__ X,
                                                 float* __restrict__ out) {
  const size_t row = blockIdx.x;
  const int tid = threadIdx.x;
  float x0 = X[(row << 9) + tid], x1 = X[(row << 9) + 256 + tid];
  float st = fmaf(x0, x0, x1 * x1);
#pragma unroll
  for (int off = 32; off; off >>= 1) st += __shfl_xor(st, off, 64);
  __shared__ float ps[4];
  if ((tid & 63) == 0) ps[tid >> 6] = st;
  __syncthreads();
  const float inv = 1.0f / sqrtf(ps[0] + ps[1] + ps[2] + ps[3]);
  out[(row << 9) + tid] = x0 * inv;
  out[(row << 9) + 256 + tid] = x1 * inv;
}

extern "C" void kernel_launch(void* const* d_in, const int* in_sizes, int n_in,
                              void* d_out, int out_size, void* d_ws, size_t ws_size,
                              hipStream_t stream) {
  const float* F_t = (const float*)d_in[0];
  const float* F_s = (const float*)d_in[1];
  const float* Wq = (const float*)d_in[2];
  const float* bq = (const float*)d_in[3];
  const float* Wk = (const float*)d_in[4];
  const float* bk = (const float*)d_in[5];
  const float* Wv = (const float*)d_in[6];
  const float* bvb = (const float*)d_in[7];
  const float* Wp = (const float*)d_in[8];
  const float* bp = (const float*)d_in[9];
  float* out = (float*)d_out;

  ushort_t* u0 = (ushort_t*)d_ws;
  ushort_t* Fth = u0;                      //  2,097,152
  ushort_t* Ftl = Fth + 2097152;
  ushort_t* Fsh = Ftl + 2097152;           //  4,718,592
  ushort_t* Fsl = Fsh + 4718592;
  ushort_t* Wqh = Fsl + 4718592;           //  262,144 each
  ushort_t* Wql = Wqh + 262144;
  ushort_t* Wkh = Wql + 262144;
  ushort_t* Wkl = Wkh + 262144;
  ushort_t* Wvh = Wkl + 262144;
  ushort_t* Wvl = Wvh + 262144;
  ushort_t* Wph = Wvl + 262144;
  ushort_t* qh = Wph + 262144;             //  2,097,152
  ushort_t* ql = qh + 2097152;
  ushort_t* kh = ql + 2097152;             //  4,718,592
  ushort_t* kl = kh + 4718592;
  ushort_t* vt = kl + 4718592;             //  4,718,592  [128][64][576]
  ushort_t* T0b = vt + 4718592;            //  2,097,152  (attn out, bf16)
  float* T1 = (float*)(T0b + 2097152);     //  2,097,152 f32
  unsigned long long* gpart = (unsigned long long*)(T1 + 2097152);  // 256*1152 ull

  const float C_mu = (float)(0.05 * log(1.0 / 256.0 + 1e-8));
  const float C_nu = (float)(0.05 * log(1.0 / 576.0 + 1e-8));

  (void)hipFuncSetAttribute((const void*)sinkhorn7_k,
                            hipFuncAttributeMaxDynamicSharedMemorySize, SK7_SMEM);

  pack_k<<<7680, 256, 0, stream>>>(F_t, F_s, Wq, Wk, Wv, Wp, Fth, Ftl, Fsh, Fsl,
                                   Wqh, Wql, Wkh, Wkl, Wvh, Wvl, Wph);
  gemmnorm2_k<<<dim3(64, 8), 256, 0, stream>>>(Fth, Ftl, Wqh, Wql, bq, qh, ql, 256);
  gemmnorm2_k<<<dim3(144, 8), 256, 0, stream>>>(Fsh, Fsl, Wkh, Wkl, bk, kh, kl, 576);
  gemmtrans2_k<<<dim3(144, 8), 256, 0, stream>>>(Fsh, Wvh, bvb, vt);
  sinkhorn7_k<<<256, 1024, SK7_SMEM, stream>>>(qh, ql, kh, kl, vt, T0b, gpart, C_mu, C_nu);
  gemmplain_k<<<dim3(64, 8), 256, 0, stream>>>(T0b, Wph, bp, T1);
  rownorm_k<<<4096, 256, 0, stream>>>(T1, out);
}

// Round 9
// 385.451 us; speedup vs baseline: 2.2695x; 2.2695x over previous
//
#include <hip/hip_runtime.h>
#include <math.h>

#define EPS_OT 0.05f
#define INV_EPS 20.0f

typedef unsigned short ushort_t;
typedef __attribute__((ext_vector_type(8))) short short8;
typedef __attribute__((ext_vector_type(4))) float f32x4;
union Pk { uint4 u; short8 s; };

__device__ __forceinline__ unsigned int f2bf(float f) {  // RNE f32->bf16
  unsigned int u = __float_as_uint(f);
  return (u + 0x7FFFu + ((u >> 16) & 1u)) >> 16;
}
__device__ __forceinline__ float bf2f(unsigned int u) { return __uint_as_float(u << 16); }

// ---------------- pack: fp32 -> hi/lo bf16 (one-time) ----------------
__global__ __launch_bounds__(256) void pack_k(const float* __restrict__ F_t,
                                              const float* __restrict__ F_s,
                                              const float* __restrict__ Wq,
                                              const float* __restrict__ Wk,
                                              const float* __restrict__ Wv,
                                              const float* __restrict__ Wp,
                                              ushort_t* __restrict__ Fth, ushort_t* __restrict__ Ftl,
                                              ushort_t* __restrict__ Fsh, ushort_t* __restrict__ Fsl,
                                              ushort_t* __restrict__ Wqh, ushort_t* __restrict__ Wql,
                                              ushort_t* __restrict__ Wkh, ushort_t* __restrict__ Wkl,
                                              ushort_t* __restrict__ Wvh, ushort_t* __restrict__ Wvl,
                                              ushort_t* __restrict__ Wph) {
  const int blk = blockIdx.x;
  const float* src; ushort_t* dh; ushort_t* dl; size_t off;
  if (blk < 2048)      { src = F_t; dh = Fth; dl = Ftl; off = (size_t)blk * 1024; }
  else if (blk < 6656) { src = F_s; dh = Fsh; dl = Fsl; off = (size_t)(blk - 2048) * 1024; }
  else if (blk < 6912) { src = Wq;  dh = Wqh; dl = Wql; off = (size_t)(blk - 6656) * 1024; }
  else if (blk < 7168) { src = Wk;  dh = Wkh; dl = Wkl; off = (size_t)(blk - 6912) * 1024; }
  else if (blk < 7424) { src = Wv;  dh = Wvh; dl = Wvl; off = (size_t)(blk - 7168) * 1024; }
  else                 { src = Wp;  dh = Wph; dl = nullptr; off = (size_t)(blk - 7424) * 1024; }
  const size_t i = off + (size_t)threadIdx.x * 4;
  float4 f = *(const float4*)(src + i);
  unsigned int h0 = f2bf(f.x), h1 = f2bf(f.y), h2 = f2bf(f.z), h3 = f2bf(f.w);
  uint2 hh; hh.x = h0 | (h1 << 16); hh.y = h2 | (h3 << 16);
  *(uint2*)(dh + i) = hh;
  if (dl) {
    uint2 ll;
    ll.x = f2bf(f.x - bf2f(h0)) | (f2bf(f.y - bf2f(h1)) << 16);
    ll.y = f2bf(f.z - bf2f(h2)) | (f2bf(f.w - bf2f(h3)) << 16);
    *(uint2*)(dl + i) = ll;
  }
}

// ====== hi/lo GEMM main loop on pre-packed bf16 (64x64 tile, K=512, 3-MFMA) ======
#define GEMM_HL_BODY()                                                                      \
  f32x4 acc[4] = {};                                                                        \
  for (int k0 = 0; k0 < 512; k0 += 64) {                                                    \
    uint4 a0 = *(const uint4*)(Xp_h + k0), a1 = *(const uint4*)(Xp_h + k0 + 8);             \
    uint4 b0 = *(const uint4*)(Xp_l + k0), b1 = *(const uint4*)(Xp_l + k0 + 8);             \
    uint4 c0 = *(const uint4*)(Wp_h + k0), c1 = *(const uint4*)(Wp_h + k0 + 8);             \
    uint4 d0 = *(const uint4*)(Wp_l + k0), d1 = *(const uint4*)(Wp_l + k0 + 8);             \
    __syncthreads();                                                                        \
    *(uint4*)&Xh[r][cg * 16] = a0; *(uint4*)&Xh[r][cg * 16 + 8] = a1;                       \
    *(uint4*)&Xl[r][cg * 16] = b0; *(uint4*)&Xl[r][cg * 16 + 8] = b1;                       \
    *(uint4*)&Wh[r][cg * 16] = c0; *(uint4*)&Wh[r][cg * 16 + 8] = c1;                       \
    *(uint4*)&Wl[r][cg * 16] = d0; *(uint4*)&Wl[r][cg * 16 + 8] = d1;                       \
    __syncthreads();                                                                        \
    _Pragma("unroll") for (int kst = 0; kst < 2; ++kst) {                                   \
      short8 ah = *(const short8*)&Xh[16 * w + li][kst * 32 + 8 * lg];                      \
      short8 al = *(const short8*)&Xl[16 * w + li][kst * 32 + 8 * lg];                      \
      _Pragma("unroll") for (int nt = 0; nt < 4; ++nt) {                                    \
        short8 bh = *(const short8*)&Wh[nt * 16 + li][kst * 32 + 8 * lg];                   \
        short8 bl = *(const short8*)&Wl[nt * 16 + li][kst * 32 + 8 * lg];                   \
        acc[nt] = __builtin_amdgcn_mfma_f32_16x16x32_bf16(ah, bh, acc[nt], 0, 0, 0);        \
        acc[nt] = __builtin_amdgcn_mfma_f32_16x16x32_bf16(ah, bl, acc[nt], 0, 0, 0);        \
        acc[nt] = __builtin_amdgcn_mfma_f32_16x16x32_bf16(al, bh, acc[nt], 0, 0, 0);        \
      }                                                                                     \
    }                                                                                       \
  }

// ====== plain bf16 GEMM main loop (64x64 tile, K=512, 1-MFMA) ======
#define GEMM_PL_BODY()                                                                      \
  f32x4 acc[4] = {};                                                                        \
  for (int k0 = 0; k0 < 512; k0 += 64) {                                                    \
    uint4 a0 = *(const uint4*)(Xp_h + k0), a1 = *(const uint4*)(Xp_h + k0 + 8);             \
    uint4 c0 = *(const uint4*)(Wp_h + k0), c1 = *(const uint4*)(Wp_h + k0 + 8);             \
    __syncthreads();                                                                        \
    *(uint4*)&Xh[r][cg * 16] = a0; *(uint4*)&Xh[r][cg * 16 + 8] = a1;                       \
    *(uint4*)&Wh[r][cg * 16] = c0; *(uint4*)&Wh[r][cg * 16 + 8] = c1;                       \
    __syncthreads();                                                                        \
    _Pragma("unroll") for (int kst = 0; kst < 2; ++kst) {                                   \
      short8 ah = *(const short8*)&Xh[16 * w + li][kst * 32 + 8 * lg];                      \
      _Pragma("unroll") for (int nt = 0; nt < 4; ++nt) {                                    \
        short8 bh = *(const short8*)&Wh[nt * 16 + li][kst * 32 + 8 * lg];                   \
        acc[nt] = __builtin_amdgcn_mfma_f32_16x16x32_bf16(ah, bh, acc[nt], 0, 0, 0);        \
      }                                                                                     \
    }                                                                                       \
  }

// ------- fused GEMM + per-head l2norm -> hi/lo bf16 [B*H][Nn][64] (q and k) -------
__global__ __launch_bounds__(256) void gemmnorm2_k(const ushort_t* __restrict__ Xg_h,
                                                   const ushort_t* __restrict__ Xg_l,
                                                   const ushort_t* __restrict__ Wg_h,
                                                   const ushort_t* __restrict__ Wg_l,
                                                   const float* __restrict__ bias,
                                                   ushort_t* __restrict__ oh,
                                                   ushort_t* __restrict__ ol, int Nn) {
  __shared__ ushort_t Xh[64][72], Xl[64][72], Wh[64][72], Wl[64][72];
  const int tid = threadIdx.x;
  const int w = tid >> 6, l = tid & 63, li = l & 15, lg = l >> 4;
  const int r = tid >> 2, cg = tid & 3;
  const int m0 = blockIdx.x << 6;
  const int h = blockIdx.y, n0 = h << 6;
  const ushort_t* Xp_h = Xg_h + (size_t)(m0 + r) * 512 + cg * 16;
  const ushort_t* Xp_l = Xg_l + (size_t)(m0 + r) * 512 + cg * 16;
  const ushort_t* Wp_h = Wg_h + (size_t)(n0 + r) * 512 + cg * 16;
  const ushort_t* Wp_l = Wg_l + (size_t)(n0 + r) * 512 + cg * 16;
  GEMM_HL_BODY()
  float v[4][4];
  float ss[4] = {0.f, 0.f, 0.f, 0.f};
#pragma unroll
  for (int nt = 0; nt < 4; ++nt) {
    float bb = bias[n0 + nt * 16 + li];
#pragma unroll
    for (int reg = 0; reg < 4; ++reg) {
      float y = acc[nt][reg] + bb;
      v[nt][reg] = y;
      ss[reg] = fmaf(y, y, ss[reg]);
    }
  }
#pragma unroll
  for (int off = 1; off < 16; off <<= 1)
#pragma unroll
    for (int reg = 0; reg < 4; ++reg) ss[reg] += __shfl_xor(ss[reg], off, 64);
  const int b = m0 / Nn;
  const int nbase = m0 - b * Nn;
  const size_t base = ((size_t)(b * 8 + h) * Nn + nbase + 16 * w + 4 * lg) * 64;
#pragma unroll
  for (int reg = 0; reg < 4; ++reg) {
    float inv = 1.0f / fmaxf(sqrtf(ss[reg]), 1e-12f);
#pragma unroll
    for (int nt = 0; nt < 4; ++nt) {
      float y = v[nt][reg] * inv;
      unsigned int hi = f2bf(y);
      size_t idx = base + (size_t)reg * 64 + nt * 16 + li;
      oh[idx] = (ushort_t)hi;
      ol[idx] = (ushort_t)f2bf(y - bf2f(hi));
    }
  }
}

// ------- fused plain-bf16 GEMM + transpose: vt[s][c 0..63][j 0..575] (v path) -------
__global__ __launch_bounds__(256) void gemmtrans2_k(const ushort_t* __restrict__ Xg_h,
                                                    const ushort_t* __restrict__ Wg_h,
                                                    const float* __restrict__ bias,
                                                    ushort_t* __restrict__ vt) {
  __shared__ ushort_t Xh[64][72], Wh[64][72];
  __shared__ ushort_t Vs[64 * 73];
  const int tid = threadIdx.x;
  const int w = tid >> 6, l = tid & 63, li = l & 15, lg = l >> 4;
  const int r = tid >> 2, cg = tid & 3;
  const int m0 = blockIdx.x << 6;
  const int h = blockIdx.y, n0 = h << 6;
  const ushort_t* Xp_h = Xg_h + (size_t)(m0 + r) * 512 + cg * 16;
  const ushort_t* Wp_h = Wg_h + (size_t)(n0 + r) * 512 + cg * 16;
  GEMM_PL_BODY()
#pragma unroll
  for (int nt = 0; nt < 4; ++nt) {
    float bb = bias[n0 + nt * 16 + li];
#pragma unroll
    for (int reg = 0; reg < 4; ++reg)
      Vs[(16 * w + 4 * lg + reg) * 73 + nt * 16 + li] = (ushort_t)f2bf(acc[nt][reg] + bb);
  }
  __syncthreads();
  const int a9 = m0 >> 6;
  const int b = a9 / 9;
  const int nbase = m0 - b * 576;
  const int s = b * 8 + h;
  const int c = tid >> 2, q4 = tid & 3;
  ushort_t tmp[16];
#pragma unroll
  for (int jj = 0; jj < 16; ++jj) tmp[jj] = Vs[(q4 * 16 + jj) * 73 + c];
  ushort_t* op = vt + ((size_t)s * 64 + c) * 576 + nbase + q4 * 16;
  *(uint4*)op = *(uint4*)&tmp[0];
  *(uint4*)(op + 8) = *(uint4*)&tmp[8];
}

// ------- final plain-bf16 GEMM (scorev-out bf16 @ Wp_h) -> fp32 -------
__global__ __launch_bounds__(256) void gemmplain_k(const ushort_t* __restrict__ Xg_h,
                                                   const ushort_t* __restrict__ Wg_h,
                                                   const float* __restrict__ bias,
                                                   float* __restrict__ Y) {
  __shared__ ushort_t Xh[64][72], Wh[64][72];
  const int tid = threadIdx.x;
  const int w = tid >> 6, l = tid & 63, li = l & 15, lg = l >> 4;
  const int r = tid >> 2, cg = tid & 3;
  const int m0 = blockIdx.x << 6, n0 = blockIdx.y << 6;
  const ushort_t* Xp_h = Xg_h + (size_t)(m0 + r) * 512 + cg * 16;
  const ushort_t* Wp_h = Wg_h + (size_t)(n0 + r) * 512 + cg * 16;
  GEMM_PL_BODY()
#pragma unroll
  for (int nt = 0; nt < 4; ++nt) {
    float bb = bias[n0 + nt * 16 + li];
#pragma unroll
    for (int reg = 0; reg < 4; ++reg)
      Y[(size_t)(m0 + 16 * w + 4 * lg + reg) * 512 + n0 + nt * 16 + li] = acc[nt][reg] + bb;
  }
}

// ---------- simE: E[s][i][j] = bf16(exp((q.k - 1)*20)), MFMA hi/lo ----------
__global__ __launch_bounds__(256) void simE2_k(const ushort_t* __restrict__ qh,
                                               const ushort_t* __restrict__ ql,
                                               const ushort_t* __restrict__ kh,
                                               const ushort_t* __restrict__ kl,
                                               ushort_t* __restrict__ E) {
  const int s = blockIdx.x, i0 = blockIdx.y << 6, j0 = blockIdx.z << 6;
  const int tid = threadIdx.x;
  const int w = tid >> 6, l = tid & 63, li = l & 15, lg = l >> 4;
  const size_t qoff = ((size_t)s * 256 + i0 + 16 * w + li) * 64 + 8 * lg;
  short8 aH0 = *(const short8*)(qh + qoff), aH1 = *(const short8*)(qh + qoff + 32);
  short8 aL0 = *(const short8*)(ql + qoff), aL1 = *(const short8*)(ql + qoff + 32);
  f32x4 acc[4] = {};
#pragma unroll
  for (int nt = 0; nt < 4; ++nt) {
    const size_t koff = ((size_t)s * 576 + j0 + nt * 16 + li) * 64 + 8 * lg;
    short8 bH0 = *(const short8*)(kh + koff), bH1 = *(const short8*)(kh + koff + 32);
    short8 bL0 = *(const short8*)(kl + koff), bL1 = *(const short8*)(kl + koff + 32);
    acc[nt] = __builtin_amdgcn_mfma_f32_16x16x32_bf16(aH0, bH0, acc[nt], 0, 0, 0);
    acc[nt] = __builtin_amdgcn_mfma_f32_16x16x32_bf16(aH1, bH1, acc[nt], 0, 0, 0);
    acc[nt] = __builtin_amdgcn_mfma_f32_16x16x32_bf16(aH0, bL0, acc[nt], 0, 0, 0);
    acc[nt] = __builtin_amdgcn_mfma_f32_16x16x32_bf16(aH1, bL1, acc[nt], 0, 0, 0);
    acc[nt] = __builtin_amdgcn_mfma_f32_16x16x32_bf16(aL0, bH0, acc[nt], 0, 0, 0);
    acc[nt] = __builtin_amdgcn_mfma_f32_16x16x32_bf16(aL1, bH1, acc[nt], 0, 0, 0);
  }
  ushort_t* Ep = E + (size_t)s * 147456;
#pragma unroll
  for (int nt = 0; nt < 4; ++nt)
#pragma unroll
    for (int reg = 0; reg < 4; ++reg) {
      float e = __expf((acc[nt][reg] - 1.0f) * INV_EPS);
      Ep[(size_t)(i0 + 16 * w + 4 * lg + reg) * 576 + j0 + nt * 16 + li] = (ushort_t)f2bf(e);
    }
}

// -------- Sinkhorn v8: R6 structure (plain-store partials, E in registers) + --------
// -------- single-bf16 au/bv (R8-verified numerics) -> 18 MFMA/wave/iter --------
#define SK_SMEM 147456

__global__ __launch_bounds__(1024, 1) void sinkhorn8_k(const ushort_t* __restrict__ E,
                                                       float* __restrict__ gA,
                                                       float* __restrict__ gB,
                                                       unsigned long long* __restrict__ gpart,
                                                       float C_mu, float C_nu) {
  extern __shared__ char smem[];
  const int g = blockIdx.x, s = g >> 1, rh = g & 1, pg = g ^ 1;
  const int tid = threadIdx.x, w = tid >> 6, l = tid & 63, li = l & 15, lg = l >> 4;
  unsigned long long* myP = gpart + (size_t)g * 1152;
  const unsigned long long* prP = gpart + (size_t)pg * 1152;

  ushort_t* Elds = (ushort_t*)smem;  // [128][576]
  {
    const uint4* Eg = (const uint4*)(E + (size_t)s * 147456 + (size_t)rh * 73728);
    uint4* El4 = (uint4*)Elds;
    for (int idx = tid; idx < 9216; idx += 1024) El4[idx] = Eg[idx];
  }
  __syncthreads();

  // A-layout frags: tiles (rt=0..7, kt=w) + extra (rtx, ktx)  [R6-proven]
  short8 afr[9];
#pragma unroll
  for (int rt = 0; rt < 8; ++rt)
    afr[rt] = *(const short8*)(Elds + (rt * 16 + li) * 576 + w * 32 + 8 * lg);
  const int rtx = w & 7, ktx = 16 + (w >> 3);
  afr[8] = *(const short8*)(Elds + (rtx * 16 + li) * 576 + ktx * 32 + 8 * lg);
  // B-layout frags  [R4-proven]
  const int ktB = w >> 2, ntb = (w & 3) * 9;
  short8 bfr[9];
#pragma unroll
  for (int p9 = 0; p9 < 9; ++p9) {
    const ushort_t* p = Elds + (ktB * 32 + 8 * lg) * 576 + (ntb + p9) * 16 + li;
    Pk pk;
    pk.u.x = (unsigned int)p[0]    | ((unsigned int)p[576]  << 16);
    pk.u.y = (unsigned int)p[1152] | ((unsigned int)p[1728] << 16);
    pk.u.z = (unsigned int)p[2304] | ((unsigned int)p[2880] << 16);
    pk.u.w = (unsigned int)p[3456] | ((unsigned int)p[4032] << 16);
    bfr[p9] = pk.s;
  }
  __syncthreads();

  // ---- overlay scratch (staging consumed; E lives in registers) ----
  float* uu = (float*)smem;                 // 128
  float* vv = uu + 128;                     // 576
  ushort_t* au = (ushort_t*)(vv + 576);     // 128 bf16
  ushort_t* bv = au + 128;                  // 576 bf16 (au+bv = 352 ushorts -> pad to 384)
  float* rpart = (float*)(au + 384 + 320);  // [18][128]  (after 352->704 pad region)
  float* colp = rpart + 2304;               // [4][576]
  float* cso = colp + 2304;                 // 576

  if (tid < 128) { uu[tid] = 0.0f; au[tid] = (ushort_t)0x3F80; }
  if (tid < 576) { vv[tid] = 0.0f; bv[tid] = (ushort_t)0x3F80; }
  __syncthreads();

  for (int t = 0; t < 100; ++t) {
    // ---- matvec2: col partials (uses OLD au; single bf16) ----
    {
      Pk ah; ah.u = *(const uint4*)(au + ktB * 32 + 8 * lg);
      float* cp = colp + (w >> 2) * 576;
#pragma unroll
      for (int p9 = 0; p9 < 9; ++p9) {
        f32x4 a2 = {0.f, 0.f, 0.f, 0.f};
        a2 = __builtin_amdgcn_mfma_f32_16x16x32_bf16(ah.s, bfr[p9], a2, 0, 0, 0);
        if (l < 16) cp[(ntb + p9) * 16 + l] = a2[0];
      }
    }
    __syncthreads();
    const int par = t & 1;
    // ---- publish colsums to partner (then fall through to matvec1) ----
    if (tid < 576) {
      float cs = colp[tid] + colp[576 + tid] + colp[1152 + tid] + colp[1728 + tid];
      cso[tid] = cs;
      unsigned long long pv = (unsigned long long)__float_as_uint(cs) |
                              ((unsigned long long)(unsigned int)(t + 1) << 32);
      __hip_atomic_store(&myP[par * 576 + tid], pv, __ATOMIC_RELAXED, __HIP_MEMORY_SCOPE_AGENT);
    }
    // ---- matvec1: row partials (uses OLD bv; single bf16); hides MALL round trip ----
    {
      Pk bh, bhx;
      bh.u = *(const uint4*)(bv + w * 32 + 8 * lg);
      bhx.u = *(const uint4*)(bv + ktx * 32 + 8 * lg);
#pragma unroll
      for (int rt = 0; rt < 8; ++rt) {
        f32x4 a1 = {0.f, 0.f, 0.f, 0.f};
        a1 = __builtin_amdgcn_mfma_f32_16x16x32_bf16(bh.s, afr[rt], a1, 0, 0, 0);
        if (l < 16) rpart[w * 128 + rt * 16 + l] = a1[0];
      }
      f32x4 a1 = {0.f, 0.f, 0.f, 0.f};
      a1 = __builtin_amdgcn_mfma_f32_16x16x32_bf16(bhx.s, afr[8], a1, 0, 0, 0);
      if (l < 16) rpart[ktx * 128 + rtx * 16 + l] = a1[0];
    }
    __syncthreads();
    // ---- u-update (tid<128) || poll partner + v-update (tid 128..703) ----
    if (tid < 128) {
      float rs = 0.0f;
#pragma unroll
      for (int kc = 0; kc < 18; ++kc) rs += rpart[kc * 128 + tid];
      float un = C_mu - EPS_OT * __logf(rs);
      uu[tid] = un;
      au[tid] = (ushort_t)f2bf(__expf(fminf(fmaxf(un * INV_EPS, -80.f), 80.f)));
    } else if (tid < 704) {
      const int j = tid - 128;
      const unsigned int tg = (unsigned int)(t + 1);
      unsigned long long p0;
      for (;;) {
        p0 = __hip_atomic_load(&prP[par * 576 + j], __ATOMIC_RELAXED, __HIP_MEMORY_SCOPE_AGENT);
        if ((unsigned int)(p0 >> 32) == tg) break;
        __builtin_amdgcn_s_sleep(1);
      }
      float tot = cso[j] + __uint_as_float((unsigned int)p0);
      float vn = C_nu - EPS_OT * __logf(tot);
      vv[j] = vn;
      bv[j] = (ushort_t)f2bf(__expf(fminf(fmaxf(vn * INV_EPS, -80.f), 80.f)));
    }
    __syncthreads();
  }
  if (tid < 128) gA[(size_t)s * 256 + rh * 128 + tid] = uu[tid] * INV_EPS;
  if (rh == 0 && tid < 576) gB[(size_t)s * 576 + tid] = vv[tid] * INV_EPS + 11.9012851f;  // +ln(147456)
}

// ---------- scorev: out(bf16) = score @ V via MFMA (hi/lo P, bf16 V) ----------
__global__ __launch_bounds__(256) void scorev2_k(const ushort_t* __restrict__ E,
                                                 const ushort_t* __restrict__ vt,
                                                 const float* __restrict__ gA,
                                                 const float* __restrict__ gB,
                                                 ushort_t* __restrict__ Y) {
  __shared__ float gBs[576];
  const int s = blockIdx.x, i0 = blockIdx.y << 6;
  const int tid = threadIdx.x;
  const int w = tid >> 6, l = tid & 63, li = l & 15, lg = l >> 4;
  for (int j = tid; j < 576; j += 256) gBs[j] = gB[(size_t)s * 576 + j];
  const float ga = gA[(size_t)s * 256 + i0 + 16 * w + li];
  const ushort_t* Erow = E + (size_t)s * 147456 + (size_t)(i0 + 16 * w + li) * 576;
  f32x4 acc[4] = {};
  __syncthreads();
  for (int kst = 0; kst < 18; ++kst) {
    const int jb = kst * 32 + 8 * lg;
    Pk eu; eu.u = *(const uint4*)(Erow + jb);
    float pv[8];
#pragma unroll
    for (int jj = 0; jj < 8; ++jj) {
      unsigned int us = (unsigned int)(unsigned short)eu.s[jj];
      float e = bf2f(us);
      float le = __logf(e);
      pv[jj] = (1.0f + EPS_OT * le) * __expf(le + ga + gBs[jb + jj]);
    }
    Pk ph, pl;
#pragma unroll
    for (int jj = 0; jj < 8; ++jj) {
      unsigned int h = f2bf(pv[jj]);
      ((unsigned short*)&ph.s)[jj] = (unsigned short)h;
      ((unsigned short*)&pl.s)[jj] = (unsigned short)f2bf(pv[jj] - bf2f(h));
    }
#pragma unroll
    for (int nt = 0; nt < 4; ++nt) {
      Pk vf; vf.u = *(const uint4*)(vt + ((size_t)s * 64 + nt * 16 + li) * 576 + jb);
      acc[nt] = __builtin_amdgcn_mfma_f32_16x16x32_bf16(ph.s, vf.s, acc[nt], 0, 0, 0);
      acc[nt] = __builtin_amdgcn_mfma_f32_16x16x32_bf16(pl.s, vf.s, acc[nt], 0, 0, 0);
    }
  }
  const int b = s >> 3, h = s & 7;
#pragma unroll
  for (int nt = 0; nt < 4; ++nt)
#pragma unroll
    for (int reg = 0; reg < 4; ++reg)
      Y[((size_t)(b * 256 + i0 + 16 * w + 4 * lg + reg) << 9) + (h << 6) + nt * 16 + li] =
          (ushort_t)f2bf(acc[nt][reg]);
}

// ------------------------- final row l2norm (plain division) -------------------------
__global__ __launch_bounds__(256) void rownorm_k(const float* __restrict__ X,
                                                 float* __restrict__ out) {
  const size_t row = blockIdx.x;
  const int tid = threadIdx.x;
  float x0 = X[(row << 9) + tid], x1 = X[(row << 9) + 256 + tid];
  float st = fmaf(x0, x0, x1 * x1);
#pragma unroll
  for (int off = 32; off; off >>= 1) st += __shfl_xor(st, off, 64);
  __shared__ float ps[4];
  if ((tid & 63) == 0) ps[tid >> 6] = st;
  __syncthreads();
  const float inv = 1.0f / sqrtf(ps[0] + ps[1] + ps[2] + ps[3]);
  out[(row << 9) + tid] = x0 * inv;
  out[(row << 9) + 256 + tid] = x1 * inv;
}

extern "C" void kernel_launch(void* const* d_in, const int* in_sizes, int n_in,
                              void* d_out, int out_size, void* d_ws, size_t ws_size,
                              hipStream_t stream) {
  const float* F_t = (const float*)d_in[0];
  const float* F_s = (const float*)d_in[1];
  const float* Wq = (const float*)d_in[2];
  const float* bq = (const float*)d_in[3];
  const float* Wk = (const float*)d_in[4];
  const float* bk = (const float*)d_in[5];
  const float* Wv = (const float*)d_in[6];
  const float* bvb = (const float*)d_in[7];
  const float* Wp = (const float*)d_in[8];
  const float* bp = (const float*)d_in[9];
  float* out = (float*)d_out;

  ushort_t* u0 = (ushort_t*)d_ws;
  ushort_t* Fth = u0;                      //  2,097,152
  ushort_t* Ftl = Fth + 2097152;
  ushort_t* Fsh = Ftl + 2097152;           //  4,718,592
  ushort_t* Fsl = Fsh + 4718592;
  ushort_t* Wqh = Fsl + 4718592;           //  262,144 each
  ushort_t* Wql = Wqh + 262144;
  ushort_t* Wkh = Wql + 262144;
  ushort_t* Wkl = Wkh + 262144;
  ushort_t* Wvh = Wkl + 262144;
  ushort_t* Wvl = Wvh + 262144;
  ushort_t* Wph = Wvl + 262144;
  ushort_t* qh = Wph + 262144;             //  2,097,152
  ushort_t* ql = qh + 2097152;
  ushort_t* kh = ql + 2097152;             //  4,718,592
  ushort_t* kl = kh + 4718592;
  ushort_t* vt = kl + 4718592;             //  4,718,592  [128][64][576]
  ushort_t* Eb = vt + 4718592;             // 18,874,368  [128][256][576]
  ushort_t* T0b = Eb + 18874368;           //  2,097,152  (scorev out bf16)
  float* T1 = (float*)(T0b + 2097152);     //  2,097,152 f32
  float* gA = T1 + 2097152;                //  32,768
  float* gB = gA + 32768;                  //  73,728
  unsigned long long* gpart = (unsigned long long*)(gB + 73728);  // 256*1152 ull

  const float C_mu = (float)(0.05 * log(1.0 / 256.0 + 1e-8));
  const float C_nu = (float)(0.05 * log(1.0 / 576.0 + 1e-8));

  (void)hipFuncSetAttribute((const void*)sinkhorn8_k,
                            hipFuncAttributeMaxDynamicSharedMemorySize, SK_SMEM);

  pack_k<<<7680, 256, 0, stream>>>(F_t, F_s, Wq, Wk, Wv, Wp, Fth, Ftl, Fsh, Fsl,
                                   Wqh, Wql, Wkh, Wkl, Wvh, Wvl, Wph);
  gemmnorm2_k<<<dim3(64, 8), 256, 0, stream>>>(Fth, Ftl, Wqh, Wql, bq, qh, ql, 256);
  gemmnorm2_k<<<dim3(144, 8), 256, 0, stream>>>(Fsh, Fsl, Wkh, Wkl, bk, kh, kl, 576);
  gemmtrans2_k<<<dim3(144, 8), 256, 0, stream>>>(Fsh, Wvh, bvb, vt);
  simE2_k<<<dim3(128, 4, 9), 256, 0, stream>>>(qh, ql, kh, kl, Eb);
  sinkhorn8_k<<<256, 1024, SK_SMEM, stream>>>(Eb, gA, gB, gpart, C_mu, C_nu);
  scorev2_k<<<dim3(128, 4), 256, 0, stream>>>(Eb, vt, gA, gB, T0b);
  gemmplain_k<<<dim3(64, 8), 256, 0, stream>>>(T0b, Wph, bp, T1);
  rownorm_k<<<4096, 256, 0, stream>>>(T1, out);
}